// Round 2
// baseline (722.680 us; speedup 1.0000x reference)
//
#include <hip/hip_runtime.h>
#include <hip/hip_bf16.h>

typedef unsigned short u16;
typedef __attribute__((ext_vector_type(8))) short bf16x8;
typedef __attribute__((ext_vector_type(4))) float f32x4;
#define MFMA16(a,b,c) __builtin_amdgcn_mfma_f32_16x16x32_bf16(a,b,c,0,0,0)
#define VPAD 100000

__device__ __forceinline__ float sigf(float x){ return 1.0f/(1.0f + __expf(-x)); }
__device__ __forceinline__ float ftanh(float x){
    float ax = fabsf(x);
    float e = __expf(-2.f*ax);
    float r = (1.f - e) / (1.f + e);
    return copysignf(r, x);
}
__device__ __forceinline__ u16 f2b(float f){
    unsigned u = __float_as_uint(f);
    u += 0x7fffu + ((u >> 16) & 1u);
    return (u16)(u >> 16);
}
__device__ __forceinline__ unsigned int pk2(float x, float y){
    return ((unsigned)f2b(y) << 16) | (unsigned)f2b(x);
}
__device__ __forceinline__ float b2f(u16 u){
    return __uint_as_float(((unsigned int)u) << 16);
}
__device__ __forceinline__ uint4 pk8(float4 x, float4 y){
    uint4 o;
    o.x = pk2(x.x,x.y); o.y = pk2(x.z,x.w);
    o.z = pk2(y.x,y.y); o.w = pk2(y.z,y.w);
    return o;
}

// ---------------------------------------------------------------------------
// prep: weight preprocessing (no emb conversion).
//  p1W/p2W f32->bf16; qWih/qWhh live-row pack (n'=4d+gate); naW frag blob;
//  bias combine.
// ---------------------------------------------------------------------------
__global__ __launch_bounds__(256) void prep_kernel(
    const float* __restrict__ p1W, const float* __restrict__ p2W,
    const float* __restrict__ naW,
    const float* __restrict__ qWih, const float* __restrict__ qWhh,
    const float* __restrict__ qBih, const float* __restrict__ qBhh,
    u16* __restrict__ p1Wb, u16* __restrict__ p2Wb,
    u16* __restrict__ nawf, u16* __restrict__ WihS, u16* __restrict__ WhhS,
    float* __restrict__ bc)
{
    const long gid = (long)blockIdx.x * 256 + threadIdx.x;
    const long E0 = 131072;         // p1W float4 units
    const long E1 = E0 + 131072;    // p2W
    const long E2 = E1 + 131072;    // Wih pack (8 u16/thread)
    const long E3 = E2 + 131072;    // Whh pack
    const long E4 = E3 + 16384;     // naW frag pack
    const long E5 = E4 + 2048;      // bias comb
    if (gid < E0){
        float4 v = reinterpret_cast<const float4*>(p1W)[gid];
        uint2 s; s.x = pk2(v.x,v.y); s.y = pk2(v.z,v.w);
        reinterpret_cast<uint2*>(p1Wb)[gid] = s;
    } else if (gid < E1){
        long i = gid - E0;
        float4 v = reinterpret_cast<const float4*>(p2W)[i];
        uint2 s; s.x = pk2(v.x,v.y); s.y = pk2(v.z,v.w);
        reinterpret_cast<uint2*>(p2Wb)[i] = s;
    } else if (gid < E2){
        long j = gid - E1;
        int n = (int)(j >> 6), c8 = (int)(j & 63);
        int srow = (n & 3) * 1024 + (n >> 2);
        const float* sp = qWih + (size_t)srow * 512 + c8 * 8;
        float4 a = *reinterpret_cast<const float4*>(sp);
        float4 b = *reinterpret_cast<const float4*>(sp + 4);
        *reinterpret_cast<uint4*>(WihS + (size_t)n*512 + c8*8) = pk8(a,b);
    } else if (gid < E3){
        long j = gid - E2;
        int n = (int)(j >> 6), c8 = (int)(j & 63);
        int srow = (n & 3) * 1024 + (n >> 2);
        const float* sp = qWhh + (size_t)srow * 1024 + c8 * 8;
        float4 a = *reinterpret_cast<const float4*>(sp);
        float4 b = *reinterpret_cast<const float4*>(sp + 4);
        *reinterpret_cast<uint4*>(WhhS + (size_t)n*512 + c8*8) = pk8(a,b);
    } else if (gid < E4){
        long j = gid - E3;                 // 0..16383
        int f = (int)(j >> 6), lane = (int)(j & 63);
        int ks = f >> 4, ig = f & 15;
        int col = lane & 15, quad = lane >> 4;
        int n = ig*16 + col;
        int k0 = ks*32 + quad*8;
        const float* sp = naW + (size_t)n*512 + k0;
        float4 a = *reinterpret_cast<const float4*>(sp);
        float4 b = *reinterpret_cast<const float4*>(sp + 4);
        *reinterpret_cast<uint4*>(nawf + j*8) = pk8(a,b);
    } else if (gid < E5){
        int n = (int)(gid - E4);
        int row = (n & 3) * 1024 + (n >> 2);
        bc[n] = qBih[row] + qBhh[row];
    }
}

// ---------------------------------------------------------------------------
// Neighbor encoder v4: one block per logical row (0..2050), both sides.
// Two K-half phases (rel, ent). Each phase: all gathers (f32 emb) issued
// upfront into a fragment-ordered 32KB LDS blob; B from frag-packed naW.
// LDS XOR swizzle (unit ^= ksl on low 4 bits) kills the 32-way write
// conflict: bank start becomes ((cl^ksl)&7)*4, spreading the half-wave
// across all 8 bank groups. Reads apply the same involution (wave-uniform
// XOR -> read conflict profile unchanged).
// ---------------------------------------------------------------------------
__global__ __launch_bounds__(256) void neighbor_v4(
    const int* __restrict__ qL, const int* __restrict__ qR,
    const int* __restrict__ sL, const int* __restrict__ sR,
    const float* __restrict__ emb,
    const u16* __restrict__ nawf,
    const float* __restrict__ naB, const float* __restrict__ nuW,
    const float* __restrict__ nuB,
    float* __restrict__ out, u16* __restrict__ out_bf)
{
    __shared__ __align__(16) u16 frg[32*512];   // 32 frags x 1KB
    __shared__ int relid[2][32];
    __shared__ int entid[2][32];
    __shared__ float logit[2][32];
    __shared__ float att[2][32];

    const int t = threadIdx.x;
    const int row = blockIdx.x;   // 0..2050
    if (t < 128){
        int s = t >> 6, j = t & 63;
        int k = j >> 1, which = j & 1;
        const int* conn;
        if (row < 2048) conn = (s ? qR : qL) + (size_t)row * 60;
        else            conn = (s ? sR : sL) + (size_t)(row - 2048) * 60;
        int id = (k < 30) ? conn[k*2 + which] : VPAD;
        if (which) entid[s][k] = id; else relid[s][k] = id;
    }
    if (t >= 128 && t < 192){ int s = (t-128) >> 5; logit[s][(t-128)&31] = 0.f; }
    __syncthreads();

    const int w = t >> 6, lane = t & 63;
    const int col = lane & 15, quad = lane >> 4;

    // decode gather unit (constant per thread across phases)
    int gc[8], gk[8], gs[8];
    #pragma unroll
    for (int i = 0; i < 8; i++){
        int idx = i*256 + t;
        gc[i] = idx & 31;            // 8-elem chunk within 256-elem half
        gk[i] = (idx >> 5) & 31;     // row 0..31
        gs[i] = idx >> 10;           // side
    }

    f32x4 acc[4][4] = {};

    #pragma unroll
    for (int p = 0; p < 2; p++){
        // gather phase p (p=0: rel, p=1: ent)
        #pragma unroll
        for (int i = 0; i < 8; i++){
            int s = gs[i], k = gk[i], c = gc[i];
            int e0 = c*8;
            int id = p ? entid[s][k] : relid[s][k];
            const float* ptr = emb + (size_t)id*256 + e0;
            float4 x = *reinterpret_cast<const float4*>(ptr);
            float4 y = *reinterpret_cast<const float4*>(ptr + 4);
            int ksl = e0 >> 5, q = (e0 >> 3) & 3;
            int mt = k >> 4, cl = k & 15;
            int ln = q*16 + (cl ^ ksl);          // XOR swizzle (bank spread)
            u16* dst = frg + ((((s*2 + mt)*8 + ksl)*64) + ln)*8;
            *reinterpret_cast<uint4*>(dst) = pk8(x, y);
        }
        __syncthreads();

        // MFMA phase: 8 local ks steps
        #pragma unroll
        for (int ksl = 0; ksl < 8; ksl++){
            const int lnR = (lane & 48) | ((lane & 15) ^ ksl);  // inverse swizzle
            bf16x8 a[4], b[4];
            #pragma unroll
            for (int u = 0; u < 4; u++)
                a[u] = *reinterpret_cast<const bf16x8*>(frg + (((u*8 + ksl)*64) + lnR)*8);
            const int ks = p*8 + ksl;
            #pragma unroll
            for (int i = 0; i < 4; i++)
                b[i] = *reinterpret_cast<const bf16x8*>(nawf + ((size_t)(ks*16 + w*4 + i)*64 + lane)*8);
            #pragma unroll
            for (int i = 0; i < 4; i++)
                #pragma unroll
                for (int u = 0; u < 4; u++)
                    acc[u][i] = MFMA16(a[u], b[i], acc[u][i]);
        }
        __syncthreads();
    }

    // logits
    float nu[4], nbv[4];
    #pragma unroll
    for (int i = 0; i < 4; i++){
        int n = (w*4 + i)*16 + col;
        nu[i] = nuW[n]; nbv[i] = naB[n];
    }
    #pragma unroll
    for (int u = 0; u < 4; u++){
        int s = u >> 1, mt = u & 1;
        #pragma unroll
        for (int r = 0; r < 4; r++){
            int m = mt*16 + quad*4 + r;
            float v = 0.f;
            #pragma unroll
            for (int i = 0; i < 4; i++)
                v += ftanh(acc[u][i][r] + nbv[i]) * nu[i];
            v += __shfl_xor(v, 1); v += __shfl_xor(v, 2);
            v += __shfl_xor(v, 4); v += __shfl_xor(v, 8);
            if (col == 0 && m < 30) atomicAdd(&logit[s][m], v);
        }
    }
    __syncthreads();

    if (t < 2){
        const int s = t;
        const float nub = nuB[0];
        float mx = -1e30f;
        float lg[30];
        #pragma unroll
        for (int k = 0; k < 30; k++){
            float L = logit[s][k] + nub;
            lg[k] = L; mx = fmaxf(mx, L);
        }
        float sm = 0.f;
        #pragma unroll
        for (int k = 0; k < 30; k++){ float e = __expf(lg[k]-mx); att[s][k] = e; sm += e; }
        float inv = 1.f / sm;
        #pragma unroll
        for (int k = 0; k < 30; k++) att[s][k] *= inv;
    }
    __syncthreads();

    // agg: thread t = column e (0..255), both sides; ent rows are L2-hot
    const int e = t;
    #pragma unroll
    for (int s = 0; s < 2; s++){
        float agg = 0.f;
        #pragma unroll
        for (int k = 0; k < 30; k++){
            int id = entid[s][k];
            agg += att[s][k] * emb[(size_t)id*256 + e];
        }
        float r = ftanh(agg);
        size_t oi = (size_t)row*512 + s*256 + e;
        out[oi] = r;
        out_bf[oi] = f2b(r);
    }
}

// ---------------------------------------------------------------------------
// gemm_tn: C[m,n] = act( A[m,:]·B[n,:] + bias[n] (+addD[m,n]) )
// A bf16 [M x lda], B bf16 [N x ldb]. 128x64 tile, 4 waves of 64x32.
// gm!=0: fused LSTM gate epilogue, LDS-staged for coalesced IO:
//   1. cooperatively load qg/cst tile (128m x 16d) into LDS (float4, 64B segs)
//   2. per-lane: shfl-combine (i,f,g,o), gate math against LDS tile,
//      write cn/hn into LDS (slot ownership exclusive per lane)
//   3. cooperatively write cst/hout tile back coalesced
//   gm==1: reads cst;  gm==2: c treated as 0 (first step; initializes cst)
// NOTE: hout must NOT alias A (blocks read full A rows while others write h)
// ---------------------------------------------------------------------------
__global__ __launch_bounds__(256) void gemm_tn(
    const u16* __restrict__ A, int lda,
    const u16* __restrict__ B, int ldb,
    const float* __restrict__ bias,
    const float* __restrict__ addD, int ldd,
    float* __restrict__ Cf, u16* __restrict__ Cbf, int ldc,
    int K, int relu,
    float* __restrict__ cst, const float* __restrict__ qgv,
    u16* __restrict__ hout, int gm)
{
    __shared__ __align__(16) u16 As[128][72];
    __shared__ __align__(16) u16 Bs[64][72];
    const int t = threadIdx.x;
    const int m0 = blockIdx.y * 128, n0 = blockIdx.x * 64;
    const int w = t >> 6, lane = t & 63;
    const int col = lane & 15, quad = lane >> 4;
    const int wm = (w & 1) * 64, wn = (w >> 1) * 32;

    int arow[4], aseg[4], brow[2], bseg[2];
    #pragma unroll
    for (int i = 0; i < 4; i++){
        int idx = i*256 + t; arow[i] = idx >> 3; aseg[i] = (idx & 7) * 8;
    }
    #pragma unroll
    for (int i = 0; i < 2; i++){
        int idx = i*256 + t; brow[i] = idx >> 3; bseg[i] = (idx & 7) * 8;
    }

    f32x4 acc[4][2] = {};

    const int KC = K >> 6;
    for (int kc = 0; kc < KC; kc++){
        uint4 av[4], bv[2];
        #pragma unroll
        for (int i = 0; i < 4; i++)
            av[i] = *reinterpret_cast<const uint4*>(A + (size_t)(m0 + arow[i])*lda + kc*64 + aseg[i]);
        #pragma unroll
        for (int i = 0; i < 2; i++)
            bv[i] = *reinterpret_cast<const uint4*>(B + (size_t)(n0 + brow[i])*ldb + kc*64 + bseg[i]);
        __syncthreads();
        #pragma unroll
        for (int i = 0; i < 4; i++)
            *reinterpret_cast<uint4*>(&As[arow[i]][aseg[i]]) = av[i];
        #pragma unroll
        for (int i = 0; i < 2; i++)
            *reinterpret_cast<uint4*>(&Bs[brow[i]][bseg[i]]) = bv[i];
        __syncthreads();
        #pragma unroll
        for (int ks = 0; ks < 2; ks++){
            const int k0 = ks*32 + quad*8;
            bf16x8 af[4], bf[2];
            #pragma unroll
            for (int i = 0; i < 4; i++) af[i] = *reinterpret_cast<const bf16x8*>(&As[wm + i*16 + col][k0]);
            #pragma unroll
            for (int j = 0; j < 2; j++) bf[j] = *reinterpret_cast<const bf16x8*>(&Bs[wn + j*16 + col][k0]);
            #pragma unroll
            for (int i = 0; i < 4; i++)
                #pragma unroll
                for (int j = 0; j < 2; j++)
                    acc[i][j] = MFMA16(af[i], bf[j], acc[i][j]);
        }
    }

    // gate-tile LDS staging (overlays As/Bs; guarded by uniform gm)
    float* qb   = reinterpret_cast<float*>(&As[0][0]);  // 8KB (<=18KB of As)
    float* cbuf = qb + 2048;                            // 8KB
    u16*   hbuf = &Bs[0][0];                            // 4KB (<=9KB of Bs)
    const int d0 = n0 >> 2;
    if (gm){
        __syncthreads();   // all MFMA ds_reads done before repurposing LDS
        #pragma unroll
        for (int u = 0; u < 2; u++){
            int idx = u*256 + t;           // 0..511
            int m = idx >> 2, dq = (idx & 3)*4;
            *reinterpret_cast<float4*>(&qb[m*16 + dq]) =
                *reinterpret_cast<const float4*>(&qgv[(size_t)(m0+m)*512 + d0 + dq]);
            if (gm == 1)
                *reinterpret_cast<float4*>(&cbuf[m*16 + dq]) =
                    *reinterpret_cast<const float4*>(&cst[(size_t)(m0+m)*512 + d0 + dq]);
        }
        __syncthreads();
    }

    #pragma unroll
    for (int j = 0; j < 2; j++){
        int n = n0 + wn + j*16 + col;
        float bj = bias[n];
        #pragma unroll
        for (int i = 0; i < 4; i++){
            #pragma unroll
            for (int r = 0; r < 4; r++){
                int m = m0 + wm + i*16 + quad*4 + r;
                float v = acc[i][j][r] + bj;
                if (addD) v += addD[(size_t)m*ldd + n];
                if (relu) v = fmaxf(v, 0.f);
                if (Cf)  Cf[(size_t)m*ldc + n] = v;
                if (Cbf) Cbf[(size_t)m*ldc + n] = f2b(v);
                if (gm){
                    // lane&3 encodes the gate of v (i,f,g,o for 0..3)
                    float t1 = __shfl_xor(v, 1);   // gate^1
                    float t2 = __shfl_xor(v, 2);   // gate^2
                    float t3 = __shfl_xor(v, 3);   // gate^3
                    if ((lane & 3) == 0){
                        // v=i, t1=f, t2=g, t3=o for d = n>>2
                        int mloc = wm + i*16 + quad*4 + r;
                        int dloc = (wn + j*16 + col) >> 2;
                        int si = mloc*16 + dloc;
                        float c0 = (gm == 2) ? 0.f : cbuf[si];
                        float cn = sigf(t1)*c0 + sigf(v)*ftanh(t2);
                        float hn = qb[si] + sigf(t3)*ftanh(cn);
                        cbuf[si] = cn;
                        hbuf[si] = f2b(hn);
                    }
                }
            }
        }
    }

    if (gm){
        __syncthreads();   // all gate slots written
        #pragma unroll
        for (int u = 0; u < 2; u++){
            int idx = u*256 + t;
            int m = idx >> 2, dq = (idx & 3)*4;
            *reinterpret_cast<float4*>(&cst[(size_t)(m0+m)*512 + d0 + dq]) =
                *reinterpret_cast<const float4*>(&cbuf[m*16 + dq]);
            *reinterpret_cast<uint2*>(&hout[(size_t)(m0+m)*512 + d0 + dq]) =
                *reinterpret_cast<const uint2*>(&hbuf[m*16 + dq]);
        }
    }
}

// ---------------------------------------------------------------------------
// LayerNorm(Z + X), ddof=1, eps on sigma. One wave per row; 2051 rows.
// ---------------------------------------------------------------------------
__global__ __launch_bounds__(256) void ln_kernel(
    const float* __restrict__ Z, const float* __restrict__ X, int N, int nquery,
    const float* __restrict__ lnA, const float* __restrict__ lnB,
    float* __restrict__ Y, u16* __restrict__ Ybf, float* __restrict__ Ycopy)
{
    const int wv = threadIdx.x >> 6, lane = threadIdx.x & 63;
    const int row = blockIdx.x * 4 + wv;
    if (row >= N) return;
    const float* z = Z + (size_t)row * 512;
    const float* x = X + (size_t)row * 512;
    float v[8];
    float s = 0.f, ss = 0.f;
    {
        float4 z0 = *reinterpret_cast<const float4*>(z + lane*8);
        float4 z1 = *reinterpret_cast<const float4*>(z + lane*8 + 4);
        float4 x0 = *reinterpret_cast<const float4*>(x + lane*8);
        float4 x1 = *reinterpret_cast<const float4*>(x + lane*8 + 4);
        v[0]=z0.x+x0.x; v[1]=z0.y+x0.y; v[2]=z0.z+x0.z; v[3]=z0.w+x0.w;
        v[4]=z1.x+x1.x; v[5]=z1.y+x1.y; v[6]=z1.z+x1.z; v[7]=z1.w+x1.w;
    }
    #pragma unroll
    for (int u = 0; u < 8; u++){ s += v[u]; ss += v[u]*v[u]; }
    #pragma unroll
    for (int d = 1; d < 64; d <<= 1){
        s  += __shfl_xor(s, d);
        ss += __shfl_xor(ss, d);
    }
    float mu  = s * (1.f/512.f);
    float var = (ss - 512.f*mu*mu) * (1.f/511.f);
    float sd  = sqrtf(fmaxf(var, 0.f));
    float inv = 1.f / (sd + 1e-3f);
    float o[8];
    #pragma unroll
    for (int u = 0; u < 8; u++){
        int e = lane*8 + u;
        o[u] = (v[u] - mu) * inv * lnA[e] + lnB[e];
    }
    float* yr = Y + (size_t)row*512 + lane*8;
    *reinterpret_cast<float4*>(yr)     = make_float4(o[0],o[1],o[2],o[3]);
    *reinterpret_cast<float4*>(yr + 4) = make_float4(o[4],o[5],o[6],o[7]);
    if (row < nquery){
        uint4 p;
        p.x = pk2(o[0],o[1]); p.y = pk2(o[2],o[3]);
        p.z = pk2(o[4],o[5]); p.w = pk2(o[6],o[7]);
        *reinterpret_cast<uint4*>(Ybf + (size_t)row*512 + lane*8) = p;
        float* cr = Ycopy + (size_t)row*512 + lane*8;
        *reinterpret_cast<float4*>(cr)     = make_float4(o[0],o[1],o[2],o[3]);
        *reinterpret_cast<float4*>(cr + 4) = make_float4(o[4],o[5],o[6],o[7]);
    }
}

// ---------------------------------------------------------------------------
// Small LSTM cell (D=512, batch=1): 128 blocks x 4 d, one wave per d
// ---------------------------------------------------------------------------
__global__ __launch_bounds__(256) void lstm_small(
    const float* __restrict__ x, const float* __restrict__ hin,
    float* __restrict__ c,
    const float* __restrict__ Wih, const float* __restrict__ Whh,
    const float* __restrict__ bih, const float* __restrict__ bhh,
    float* __restrict__ hout)
{
    __shared__ float xs[512], hs[512];
    __shared__ float gbuf[4][4];
    const int t = threadIdx.x;
    for (int i = t; i < 512; i += 256){ xs[i] = x[i]; hs[i] = hin[i]; }
    __syncthreads();

    const int wd = t >> 6;
    const int lane = t & 63;
    const int g = lane >> 4, p = lane & 15;
    const int d = blockIdx.x*4 + wd;
    const int j = g*512 + d;
    const float4* wi = reinterpret_cast<const float4*>(Wih + (size_t)j*512) + p*8;
    const float4* wh = reinterpret_cast<const float4*>(Whh + (size_t)j*512) + p*8;
    float acc = 0.f;
    #pragma unroll
    for (int q = 0; q < 8; q++){
        float4 wv = wi[q];
        const int kb = p*32 + q*4;
        acc += xs[kb]*wv.x + xs[kb+1]*wv.y + xs[kb+2]*wv.z + xs[kb+3]*wv.w;
        float4 vv = wh[q];
        acc += hs[kb]*vv.x + hs[kb+1]*vv.y + hs[kb+2]*vv.z + hs[kb+3]*vv.w;
    }
    acc += __shfl_xor(acc, 1); acc += __shfl_xor(acc, 2);
    acc += __shfl_xor(acc, 4); acc += __shfl_xor(acc, 8);
    if (p == 0) gbuf[wd][g] = acc + bih[j] + bhh[j];
    __syncthreads();
    if (t < 4){
        int dd = blockIdx.x*4 + t;
        float iv = gbuf[t][0], fv = gbuf[t][1], gv = gbuf[t][2], ov = gbuf[t][3];
        float cn = sigf(fv)*c[dd] + sigf(iv)*ftanh(gv);
        float hn = sigf(ov)*ftanh(cn);
        c[dd] = cn; hout[dd] = hn;
    }
}

// ---------------------------------------------------------------------------
// ae_loss + sge_enc (singleton softmax == 1)
// ---------------------------------------------------------------------------
__global__ __launch_bounds__(256) void finalize_kernel(
    const float* __restrict__ sg, const float* __restrict__ enc,
    const float* __restrict__ dec, float* __restrict__ sgeenc,
    float* __restrict__ outp)
{
    __shared__ float red[4];
    const int t = threadIdx.x;
    float s = 0.f;
    for (int i = t; i < 1536; i += 256){ float d = sg[i] - dec[i]; s += d*d; }
    s += __shfl_xor(s,1); s += __shfl_xor(s,2); s += __shfl_xor(s,4);
    s += __shfl_xor(s,8); s += __shfl_xor(s,16); s += __shfl_xor(s,32);
    if ((t & 63) == 0) red[t>>6] = s;
    __syncthreads();
    if (t == 0){
        float tot = (red[0]+red[1]+red[2]+red[3]) * (1.f/1536.f);
        outp[2048] = tot;
    }
    for (int d = t; d < 512; d += 256){
        float v = sg[d] + enc[d] + sg[512+d] + enc[512+d] + sg[1024+d] + enc[1024+d];
        sgeenc[d] = v;
        outp[2049 + d] = v;
    }
}

// ---------------------------------------------------------------------------
// wvec[n'] = sum_j sge[j] * qWhh[(n'&3)*1024 + (n'>>2), 512+j]
// ---------------------------------------------------------------------------
__global__ __launch_bounds__(256) void wvec_kernel(
    const float* __restrict__ qWhh, const float* __restrict__ sge,
    float* __restrict__ wvec)
{
    __shared__ float ss[512];
    const int t = threadIdx.x;
    for (int i = t; i < 512; i += 256) ss[i] = sge[i];
    __syncthreads();
    const int n = blockIdx.x * 256 + t;
    const int row = (n & 3) * 1024 + (n >> 2);
    const float4* w = reinterpret_cast<const float4*>(qWhh + (size_t)row*1024 + 512);
    float acc = 0.f;
    for (int kc = 0; kc < 128; kc++){
        float4 wv = w[kc];
        const int kb = kc*4;
        acc += ss[kb]*wv.x + ss[kb+1]*wv.y + ss[kb+2]*wv.z + ss[kb+3]*wv.w;
    }
    wvec[n] = acc;
}

// ---------------------------------------------------------------------------
// Gate math on packed G (kept for safety/fallback; unused in launch)
// ---------------------------------------------------------------------------
__global__ __launch_bounds__(256) void gate_kernel(
    const float* __restrict__ G, const float* __restrict__ qg,
    float* __restrict__ c, u16* __restrict__ h_bf)
{
    const int idx = blockIdx.x * 256 + threadIdx.x;
    const int b = idx >> 9, d = idx & 511;
    float4 g4 = *reinterpret_cast<const float4*>(G + (size_t)b*2048 + d*4);
    float cn = sigf(g4.y)*c[idx] + sigf(g4.x)*ftanh(g4.z);
    float hn = qg[idx] + sigf(g4.w)*ftanh(cn);
    c[idx] = cn; h_bf[idx] = f2b(hn);
}

// ---------------------------------------------------------------------------
// matching_scores[b] = dot(h[b], sge_enc)
// ---------------------------------------------------------------------------
__global__ __launch_bounds__(256) void scores_kernel(
    const u16* __restrict__ h, const float* __restrict__ sge,
    float* __restrict__ out)
{
    const int wave = threadIdx.x >> 6, lane = threadIdx.x & 63;
    const int row = blockIdx.x * 4 + wave;
    const u16* hr = h + (size_t)row * 512;
    float s = 0.f;
    for (int i = lane; i < 512; i += 64) s += b2f(hr[i]) * sge[i];
    s += __shfl_xor(s,1); s += __shfl_xor(s,2); s += __shfl_xor(s,4);
    s += __shfl_xor(s,8); s += __shfl_xor(s,16); s += __shfl_xor(s,32);
    if (lane == 0) out[row] = s;
}

// ---------------------------------------------------------------------------
extern "C" void kernel_launch(void* const* d_in, const int* in_sizes, int n_in,
                              void* d_out, int out_size, void* d_ws, size_t ws_size,
                              hipStream_t stream)
{
    (void)in_sizes; (void)n_in; (void)out_size; (void)ws_size;

    const int* qlc = (const int*)d_in[2];
    const int* qrc = (const int*)d_in[4];
    const int* slc = (const int*)d_in[6];
    const int* src = (const int*)d_in[8];
    const float* emb = (const float*)d_in[10];
    const float* naW = (const float*)d_in[11];
    const float* naB = (const float*)d_in[12];
    const float* nuW = (const float*)d_in[13];
    const float* nuB = (const float*)d_in[14];
    const float* p1W = (const float*)d_in[15], *p1b = (const float*)d_in[16];
    const float* p2W = (const float*)d_in[17], *p2b = (const float*)d_in[18];
    const float* lnA = (const float*)d_in[19], *lnB = (const float*)d_in[20];
    const float* eWih = (const float*)d_in[21], *eWhh = (const float*)d_in[22];
    const float* eBih = (const float*)d_in[23], *eBhh = (const float*)d_in[24];
    const float* dWih = (const float*)d_in[25], *dWhh = (const float*)d_in[26];
    const float* dBih = (const float*)d_in[27], *dBhh = (const float*)d_in[28];
    const float* qWih = (const float*)d_in[33], *qWhh = (const float*)d_in[34];
    const float* qBih = (const float*)d_in[35], *qBhh = (const float*)d_in[36];
    float* out = (float*)d_out;

    float* w = (float*)d_ws;
    size_t off = 0;
    auto alloc = [&](size_t nelem){ float* p = w + off; off += nelem; return p; };
    float* qn    = alloc(2176ull*512);   // neighbor f32 (2051 rows used)
    float* qg    = alloc(2176ull*512);   // query_g f32 (+ sg rows 2048..2050)
    float* enc   = alloc(1536);
    float* dec   = alloc(1536);
    float* zc    = alloc(1024);
    float* sgee  = alloc(512);
    float* wv    = alloc(2048);
    float* bc    = alloc(2048);
    float* nawfF = alloc(65536);         // 131072 u16 frag-packed naW
    float* base  = alloc(2048ull*2048);  // + Zq, qn_bf aliases
    float* G     = alloc(2048ull*2048);  // + Hq_bf, qg_bf, h ping-pong aliases
    float* cb    = alloc(2048ull*512);
    float* hbfF  = alloc(524288);        // h bf16
    float* p1WbF = alloc(262144);
    float* p2WbF = alloc(262144);
    float* WihSF = alloc(524288);
    float* WhhSF = alloc(524288);

    u16* nawf   = (u16*)nawfF;
    u16* p1Wb   = (u16*)p1WbF;
    u16* p2Wb   = (u16*)p2WbF;
    u16* WihSel = (u16*)WihSF;
    u16* WhhSel = (u16*)WhhSF;
    u16* h_bf   = (u16*)hbfF;
    float* Zq   = base;                       // 2176x512 f32
    u16* qn_bf  = (u16*)(base + 2097152);     // 2176x512 u16
    u16* Hq_bf  = (u16*)G;                    // 2176x1024 u16 (support scratch;
                                              //  reused as h ping-pong after)
    u16* qg_bf  = (u16*)(G + 2097152);        // 2176x512 u16 (2048 used)
    float* sg   = qg + 2048ull*512;
    float* zbuf = zc;
    float* cst  = zc + 512;

    hipMemsetAsync(zc, 0, 1024*sizeof(float), stream);

    // weight preprocessing (no emb conversion)
    prep_kernel<<<2120, 256, 0, stream>>>(p1W, p2W, naW, qWih, qWhh, qBih, qBhh,
                                          p1Wb, p2Wb, nawf, WihSel, WhhSel, bc);

    // neighbor encoder: 2051 rows (2048 query + 3 support), both sides
    neighbor_v4<<<2051, 256, 0, stream>>>(qlc, qrc, slc, src, emb,
                                          nawf, naB, nuW, nuB, qn, qn_bf);

    // support encoder fused over 2051 rows: H=relu(X@p1W^T+b); Z=H@p2W^T+b; LN
    gemm_tn<<<dim3(16,17), 256, 0, stream>>>(qn_bf, 512, p1Wb, 512, p1b, nullptr, 0,
                                             nullptr, Hq_bf, 1024, 512, 1,
                                             nullptr, nullptr, nullptr, 0);
    gemm_tn<<<dim3(8,17), 256, 0, stream>>>(Hq_bf, 1024, p2Wb, 1024, p2b, nullptr, 0,
                                            Zq, nullptr, 512, 1024, 0,
                                            nullptr, nullptr, nullptr, 0);
    ln_kernel<<<513, 256, 0, stream>>>(Zq, qn, 2051, 2048, lnA, lnB, qg, qg_bf, out + 2561);

    // set autoencoder
    lstm_small<<<128, 256, 0, stream>>>(sg,        zbuf,      cst, eWih, eWhh, eBih, eBhh, enc);
    lstm_small<<<128, 256, 0, stream>>>(sg + 512,  enc,       cst, eWih, eWhh, eBih, eBhh, enc + 512);
    lstm_small<<<128, 256, 0, stream>>>(sg + 1024, enc + 512, cst, eWih, eWhh, eBih, eBhh, enc + 1024);
    lstm_small<<<128, 256, 0, stream>>>(enc + 1024, enc + 1024, cst, dWih, dWhh, dBih, dBhh, dec);
    lstm_small<<<128, 256, 0, stream>>>(dec,        dec,        cst, dWih, dWhh, dBih, dBhh, dec + 512);
    lstm_small<<<128, 256, 0, stream>>>(dec + 512,  dec + 512,  cst, dWih, dWhh, dBih, dBhh, dec + 1024);

    finalize_kernel<<<1, 256, 0, stream>>>(sg, enc, dec, sgee, out);
    wvec_kernel<<<8, 256, 0, stream>>>(qWhh, sgee, wv);

    // query encoder, gate-fused:
    //   base step: base = qg@WihSel^T + bc (stored for addD) + gate(c=0) -> h_bf
    //   steps 1..3: gate(  h@WhhSel^T + wv + base ) with h ping-pong
    //   (no cb memset needed: gm=2 writes every (b,d) of cb)
    gemm_tn<<<dim3(32,16), 256, 0, stream>>>(qg_bf, 512, WihSel, 512, bc, nullptr, 0,
                                             base, nullptr, 2048, 512, 0,
                                             cb, qg, h_bf, 2);
    u16* hA = h_bf;
    u16* hB = Hq_bf;   // support scratch, free now; hout must not alias A
    for (int s = 0; s < 3; s++){
        gemm_tn<<<dim3(32,16), 256, 0, stream>>>(hA, 512, WhhSel, 512, wv, base, 2048,
                                                 nullptr, nullptr, 2048, 512, 0,
                                                 cb, qg, hB, 1);
        u16* tmp = hA; hA = hB; hB = tmp;
    }

    scores_kernel<<<512, 256, 0, stream>>>(hA, sgee, out);
}

// Round 5
// 628.872 us; speedup vs baseline: 1.1492x; 1.1492x over previous
//
#include <hip/hip_runtime.h>
#include <hip/hip_bf16.h>

typedef unsigned short u16;
typedef __attribute__((ext_vector_type(8))) short bf16x8;
typedef __attribute__((ext_vector_type(4))) float f32x4;
#define MFMA16(a,b,c) __builtin_amdgcn_mfma_f32_16x16x32_bf16(a,b,c,0,0,0)
#define VPAD 100000

__device__ __forceinline__ float sigf(float x){ return 1.0f/(1.0f + __expf(-x)); }
__device__ __forceinline__ float ftanh(float x){
    float ax = fabsf(x);
    float e = __expf(-2.f*ax);
    float r = (1.f - e) / (1.f + e);
    return copysignf(r, x);
}
__device__ __forceinline__ u16 f2b(float f){
    unsigned u = __float_as_uint(f);
    u += 0x7fffu + ((u >> 16) & 1u);
    return (u16)(u >> 16);
}
__device__ __forceinline__ unsigned int pk2(float x, float y){
    return ((unsigned)f2b(y) << 16) | (unsigned)f2b(x);
}
__device__ __forceinline__ float b2f(u16 u){
    return __uint_as_float(((unsigned int)u) << 16);
}
__device__ __forceinline__ uint4 pk8(float4 x, float4 y){
    uint4 o;
    o.x = pk2(x.x,x.y); o.y = pk2(x.z,x.w);
    o.z = pk2(y.x,y.y); o.w = pk2(y.z,y.w);
    return o;
}

// ---------------------------------------------------------------------------
// prep: weight preprocessing (no emb conversion).
//  p1W/p2W f32->bf16; qWih/qWhh live-row pack (n'=4d+gate); naW frag blob;
//  bias combine.
// ---------------------------------------------------------------------------
__global__ __launch_bounds__(256) void prep_kernel(
    const float* __restrict__ p1W, const float* __restrict__ p2W,
    const float* __restrict__ naW,
    const float* __restrict__ qWih, const float* __restrict__ qWhh,
    const float* __restrict__ qBih, const float* __restrict__ qBhh,
    u16* __restrict__ p1Wb, u16* __restrict__ p2Wb,
    u16* __restrict__ nawf, u16* __restrict__ WihS, u16* __restrict__ WhhS,
    float* __restrict__ bc)
{
    const long gid = (long)blockIdx.x * 256 + threadIdx.x;
    const long E0 = 131072;         // p1W float4 units
    const long E1 = E0 + 131072;    // p2W
    const long E2 = E1 + 131072;    // Wih pack (8 u16/thread)
    const long E3 = E2 + 131072;    // Whh pack
    const long E4 = E3 + 16384;     // naW frag pack
    const long E5 = E4 + 2048;      // bias comb
    if (gid < E0){
        float4 v = reinterpret_cast<const float4*>(p1W)[gid];
        uint2 s; s.x = pk2(v.x,v.y); s.y = pk2(v.z,v.w);
        reinterpret_cast<uint2*>(p1Wb)[gid] = s;
    } else if (gid < E1){
        long i = gid - E0;
        float4 v = reinterpret_cast<const float4*>(p2W)[i];
        uint2 s; s.x = pk2(v.x,v.y); s.y = pk2(v.z,v.w);
        reinterpret_cast<uint2*>(p2Wb)[i] = s;
    } else if (gid < E2){
        long j = gid - E1;
        int n = (int)(j >> 6), c8 = (int)(j & 63);
        int srow = (n & 3) * 1024 + (n >> 2);
        const float* sp = qWih + (size_t)srow * 512 + c8 * 8;
        float4 a = *reinterpret_cast<const float4*>(sp);
        float4 b = *reinterpret_cast<const float4*>(sp + 4);
        *reinterpret_cast<uint4*>(WihS + (size_t)n*512 + c8*8) = pk8(a,b);
    } else if (gid < E3){
        long j = gid - E2;
        int n = (int)(j >> 6), c8 = (int)(j & 63);
        int srow = (n & 3) * 1024 + (n >> 2);
        const float* sp = qWhh + (size_t)srow * 1024 + c8 * 8;
        float4 a = *reinterpret_cast<const float4*>(sp);
        float4 b = *reinterpret_cast<const float4*>(sp + 4);
        *reinterpret_cast<uint4*>(WhhS + (size_t)n*512 + c8*8) = pk8(a,b);
    } else if (gid < E4){
        long j = gid - E3;                 // 0..16383
        int f = (int)(j >> 6), lane = (int)(j & 63);
        int ks = f >> 4, ig = f & 15;
        int col = lane & 15, quad = lane >> 4;
        int n = ig*16 + col;
        int k0 = ks*32 + quad*8;
        const float* sp = naW + (size_t)n*512 + k0;
        float4 a = *reinterpret_cast<const float4*>(sp);
        float4 b = *reinterpret_cast<const float4*>(sp + 4);
        *reinterpret_cast<uint4*>(nawf + j*8) = pk8(a,b);
    } else if (gid < E5){
        int n = (int)(gid - E4);
        int row = (n & 3) * 1024 + (n >> 2);
        bc[n] = qBih[row] + qBhh[row];
    }
}

// ---------------------------------------------------------------------------
// Neighbor encoder v4: one block per logical row (0..2050), both sides.
// Two K-half phases (rel, ent). Each phase: all gathers (f32 emb) issued
// upfront into a fragment-ordered 32KB LDS blob (max MLP, conflict-free
// ds_read_b128 in MFMA phase); B from frag-packed naW (L2, 4 MFMAs/load).
// NOTE: ds_write bank conflicts here are NOT on the critical path (gather-
// latency bound; swizzle fix raised VGPR 80->100 and cost 22us — reverted).
// ---------------------------------------------------------------------------
__global__ __launch_bounds__(256) void neighbor_v4(
    const int* __restrict__ qL, const int* __restrict__ qR,
    const int* __restrict__ sL, const int* __restrict__ sR,
    const float* __restrict__ emb,
    const u16* __restrict__ nawf,
    const float* __restrict__ naB, const float* __restrict__ nuW,
    const float* __restrict__ nuB,
    float* __restrict__ out, u16* __restrict__ out_bf)
{
    __shared__ __align__(16) u16 frg[32*512];   // 32 frags x 1KB
    __shared__ int relid[2][32];
    __shared__ int entid[2][32];
    __shared__ float logit[2][32];
    __shared__ float att[2][32];

    const int t = threadIdx.x;
    const int row = blockIdx.x;   // 0..2050
    if (t < 128){
        int s = t >> 6, j = t & 63;
        int k = j >> 1, which = j & 1;
        const int* conn;
        if (row < 2048) conn = (s ? qR : qL) + (size_t)row * 60;
        else            conn = (s ? sR : sL) + (size_t)(row - 2048) * 60;
        int id = (k < 30) ? conn[k*2 + which] : VPAD;
        if (which) entid[s][k] = id; else relid[s][k] = id;
    }
    if (t >= 128 && t < 192){ int s = (t-128) >> 5; logit[s][(t-128)&31] = 0.f; }
    __syncthreads();

    const int w = t >> 6, lane = t & 63;
    const int col = lane & 15, quad = lane >> 4;

    // decode gather unit (constant per thread across phases)
    int gc[8], gk[8], gs[8];
    #pragma unroll
    for (int i = 0; i < 8; i++){
        int idx = i*256 + t;
        gc[i] = idx & 31;            // 8-elem chunk within 256-elem half
        gk[i] = (idx >> 5) & 31;     // row 0..31
        gs[i] = idx >> 10;           // side
    }

    f32x4 acc[4][4] = {};

    #pragma unroll
    for (int p = 0; p < 2; p++){
        // gather phase p (p=0: rel, p=1: ent)
        #pragma unroll
        for (int i = 0; i < 8; i++){
            int s = gs[i], k = gk[i], c = gc[i];
            int e0 = c*8;
            int id = p ? entid[s][k] : relid[s][k];
            const float* ptr = emb + (size_t)id*256 + e0;
            float4 x = *reinterpret_cast<const float4*>(ptr);
            float4 y = *reinterpret_cast<const float4*>(ptr + 4);
            int ksl = e0 >> 5, q = (e0 >> 3) & 3;
            int mt = k >> 4, cl = k & 15;
            int ln = q*16 + cl;
            u16* dst = frg + ((((s*2 + mt)*8 + ksl)*64) + ln)*8;
            *reinterpret_cast<uint4*>(dst) = pk8(x, y);
        }
        __syncthreads();

        // MFMA phase: 8 local ks steps
        #pragma unroll
        for (int ksl = 0; ksl < 8; ksl++){
            bf16x8 a[4], b[4];
            #pragma unroll
            for (int u = 0; u < 4; u++)
                a[u] = *reinterpret_cast<const bf16x8*>(frg + (((u*8 + ksl)*64) + lane)*8);
            const int ks = p*8 + ksl;
            #pragma unroll
            for (int i = 0; i < 4; i++)
                b[i] = *reinterpret_cast<const bf16x8*>(nawf + ((size_t)(ks*16 + w*4 + i)*64 + lane)*8);
            #pragma unroll
            for (int i = 0; i < 4; i++)
                #pragma unroll
                for (int u = 0; u < 4; u++)
                    acc[u][i] = MFMA16(a[u], b[i], acc[u][i]);
        }
        __syncthreads();
    }

    // logits
    float nu[4], nbv[4];
    #pragma unroll
    for (int i = 0; i < 4; i++){
        int n = (w*4 + i)*16 + col;
        nu[i] = nuW[n]; nbv[i] = naB[n];
    }
    #pragma unroll
    for (int u = 0; u < 4; u++){
        int s = u >> 1, mt = u & 1;
        #pragma unroll
        for (int r = 0; r < 4; r++){
            int m = mt*16 + quad*4 + r;
            float v = 0.f;
            #pragma unroll
            for (int i = 0; i < 4; i++)
                v += ftanh(acc[u][i][r] + nbv[i]) * nu[i];
            v += __shfl_xor(v, 1); v += __shfl_xor(v, 2);
            v += __shfl_xor(v, 4); v += __shfl_xor(v, 8);
            if (col == 0 && m < 30) atomicAdd(&logit[s][m], v);
        }
    }
    __syncthreads();

    if (t < 2){
        const int s = t;
        const float nub = nuB[0];
        float mx = -1e30f;
        float lg[30];
        #pragma unroll
        for (int k = 0; k < 30; k++){
            float L = logit[s][k] + nub;
            lg[k] = L; mx = fmaxf(mx, L);
        }
        float sm = 0.f;
        #pragma unroll
        for (int k = 0; k < 30; k++){ float e = __expf(lg[k]-mx); att[s][k] = e; sm += e; }
        float inv = 1.f / sm;
        #pragma unroll
        for (int k = 0; k < 30; k++) att[s][k] *= inv;
    }
    __syncthreads();

    // agg: thread t = column e (0..255), both sides; ent rows are L2-hot
    const int e = t;
    #pragma unroll
    for (int s = 0; s < 2; s++){
        float agg = 0.f;
        #pragma unroll
        for (int k = 0; k < 30; k++){
            int id = entid[s][k];
            agg += att[s][k] * emb[(size_t)id*256 + e];
        }
        float r = ftanh(agg);
        size_t oi = (size_t)row*512 + s*256 + e;
        out[oi] = r;
        out_bf[oi] = f2b(r);
    }
}

// ---------------------------------------------------------------------------
// gemm_tn: C[m,n] = act( A[m,:]·B[n,:] + bias[n] (+addD[m,n]) )
// A bf16 [M x lda], B bf16 [N x ldb]. 128x64 tile, 4 waves of 64x32.
// ---------------------------------------------------------------------------
__global__ __launch_bounds__(256) void gemm_tn(
    const u16* __restrict__ A, int lda,
    const u16* __restrict__ B, int ldb,
    const float* __restrict__ bias,
    const float* __restrict__ addD, int ldd,
    float* __restrict__ Cf, u16* __restrict__ Cbf, int ldc,
    int K, int relu)
{
    __shared__ __align__(16) u16 As[128][72];
    __shared__ __align__(16) u16 Bs[64][72];
    const int t = threadIdx.x;
    const int m0 = blockIdx.y * 128, n0 = blockIdx.x * 64;
    const int w = t >> 6, lane = t & 63;
    const int col = lane & 15, quad = lane >> 4;
    const int wm = (w & 1) * 64, wn = (w >> 1) * 32;

    int arow[4], aseg[4], brow[2], bseg[2];
    #pragma unroll
    for (int i = 0; i < 4; i++){
        int idx = i*256 + t; arow[i] = idx >> 3; aseg[i] = (idx & 7) * 8;
    }
    #pragma unroll
    for (int i = 0; i < 2; i++){
        int idx = i*256 + t; brow[i] = idx >> 3; bseg[i] = (idx & 7) * 8;
    }

    f32x4 acc[4][2] = {};

    const int KC = K >> 6;
    for (int kc = 0; kc < KC; kc++){
        uint4 av[4], bv[2];
        #pragma unroll
        for (int i = 0; i < 4; i++)
            av[i] = *reinterpret_cast<const uint4*>(A + (size_t)(m0 + arow[i])*lda + kc*64 + aseg[i]);
        #pragma unroll
        for (int i = 0; i < 2; i++)
            bv[i] = *reinterpret_cast<const uint4*>(B + (size_t)(n0 + brow[i])*ldb + kc*64 + bseg[i]);
        __syncthreads();
        #pragma unroll
        for (int i = 0; i < 4; i++)
            *reinterpret_cast<uint4*>(&As[arow[i]][aseg[i]]) = av[i];
        #pragma unroll
        for (int i = 0; i < 2; i++)
            *reinterpret_cast<uint4*>(&Bs[brow[i]][bseg[i]]) = bv[i];
        __syncthreads();
        #pragma unroll
        for (int ks = 0; ks < 2; ks++){
            const int k0 = ks*32 + quad*8;
            bf16x8 af[4], bf[2];
            #pragma unroll
            for (int i = 0; i < 4; i++) af[i] = *reinterpret_cast<const bf16x8*>(&As[wm + i*16 + col][k0]);
            #pragma unroll
            for (int j = 0; j < 2; j++) bf[j] = *reinterpret_cast<const bf16x8*>(&Bs[wn + j*16 + col][k0]);
            #pragma unroll
            for (int i = 0; i < 4; i++)
                #pragma unroll
                for (int j = 0; j < 2; j++)
                    acc[i][j] = MFMA16(af[i], bf[j], acc[i][j]);
        }
    }

    #pragma unroll
    for (int j = 0; j < 2; j++){
        int n = n0 + wn + j*16 + col;
        float bj = bias[n];
        #pragma unroll
        for (int i = 0; i < 4; i++){
            #pragma unroll
            for (int r = 0; r < 4; r++){
                int m = m0 + wm + i*16 + quad*4 + r;
                float v = acc[i][j][r] + bj;
                if (addD) v += addD[(size_t)m*ldd + n];
                if (relu) v = fmaxf(v, 0.f);
                if (Cf)  Cf[(size_t)m*ldc + n] = v;
                if (Cbf) Cbf[(size_t)m*ldc + n] = f2b(v);
            }
        }
    }
}

// ---------------------------------------------------------------------------
// LayerNorm(Z + X), ddof=1, eps on sigma. One wave per row; 2051 rows.
// ---------------------------------------------------------------------------
__global__ __launch_bounds__(256) void ln_kernel(
    const float* __restrict__ Z, const float* __restrict__ X, int N, int nquery,
    const float* __restrict__ lnA, const float* __restrict__ lnB,
    float* __restrict__ Y, u16* __restrict__ Ybf, float* __restrict__ Ycopy)
{
    const int wv = threadIdx.x >> 6, lane = threadIdx.x & 63;
    const int row = blockIdx.x * 4 + wv;
    if (row >= N) return;
    const float* z = Z + (size_t)row * 512;
    const float* x = X + (size_t)row * 512;
    float v[8];
    float s = 0.f, ss = 0.f;
    {
        float4 z0 = *reinterpret_cast<const float4*>(z + lane*8);
        float4 z1 = *reinterpret_cast<const float4*>(z + lane*8 + 4);
        float4 x0 = *reinterpret_cast<const float4*>(x + lane*8);
        float4 x1 = *reinterpret_cast<const float4*>(x + lane*8 + 4);
        v[0]=z0.x+x0.x; v[1]=z0.y+x0.y; v[2]=z0.z+x0.z; v[3]=z0.w+x0.w;
        v[4]=z1.x+x1.x; v[5]=z1.y+x1.y; v[6]=z1.z+x1.z; v[7]=z1.w+x1.w;
    }
    #pragma unroll
    for (int u = 0; u < 8; u++){ s += v[u]; ss += v[u]*v[u]; }
    #pragma unroll
    for (int d = 1; d < 64; d <<= 1){
        s  += __shfl_xor(s, d);
        ss += __shfl_xor(ss, d);
    }
    float mu  = s * (1.f/512.f);
    float var = (ss - 512.f*mu*mu) * (1.f/511.f);
    float sd  = sqrtf(fmaxf(var, 0.f));
    float inv = 1.f / (sd + 1e-3f);
    float o[8];
    #pragma unroll
    for (int u = 0; u < 8; u++){
        int e = lane*8 + u;
        o[u] = (v[u] - mu) * inv * lnA[e] + lnB[e];
    }
    float* yr = Y + (size_t)row*512 + lane*8;
    *reinterpret_cast<float4*>(yr)     = make_float4(o[0],o[1],o[2],o[3]);
    *reinterpret_cast<float4*>(yr + 4) = make_float4(o[4],o[5],o[6],o[7]);
    if (row < nquery){
        uint4 p;
        p.x = pk2(o[0],o[1]); p.y = pk2(o[2],o[3]);
        p.z = pk2(o[4],o[5]); p.w = pk2(o[6],o[7]);
        *reinterpret_cast<uint4*>(Ybf + (size_t)row*512 + lane*8) = p;
        float* cr = Ycopy + (size_t)row*512 + lane*8;
        *reinterpret_cast<float4*>(cr)     = make_float4(o[0],o[1],o[2],o[3]);
        *reinterpret_cast<float4*>(cr + 4) = make_float4(o[4],o[5],o[6],o[7]);
    }
}

// ---------------------------------------------------------------------------
// Small LSTM cell (D=512, batch=1): 128 blocks x 4 d, one wave per d
// ---------------------------------------------------------------------------
__global__ __launch_bounds__(256) void lstm_small(
    const float* __restrict__ x, const float* __restrict__ hin,
    float* __restrict__ c,
    const float* __restrict__ Wih, const float* __restrict__ Whh,
    const float* __restrict__ bih, const float* __restrict__ bhh,
    float* __restrict__ hout)
{
    __shared__ float xs[512], hs[512];
    __shared__ float gbuf[4][4];
    const int t = threadIdx.x;
    for (int i = t; i < 512; i += 256){ xs[i] = x[i]; hs[i] = hin[i]; }
    __syncthreads();

    const int wd = t >> 6;
    const int lane = t & 63;
    const int g = lane >> 4, p = lane & 15;
    const int d = blockIdx.x*4 + wd;
    const int j = g*512 + d;
    const float4* wi = reinterpret_cast<const float4*>(Wih + (size_t)j*512) + p*8;
    const float4* wh = reinterpret_cast<const float4*>(Whh + (size_t)j*512) + p*8;
    float acc = 0.f;
    #pragma unroll
    for (int q = 0; q < 8; q++){
        float4 wv = wi[q];
        const int kb = p*32 + q*4;
        acc += xs[kb]*wv.x + xs[kb+1]*wv.y + xs[kb+2]*wv.z + xs[kb+3]*wv.w;
        float4 vv = wh[q];
        acc += hs[kb]*vv.x + hs[kb+1]*vv.y + hs[kb+2]*vv.z + hs[kb+3]*vv.w;
    }
    acc += __shfl_xor(acc, 1); acc += __shfl_xor(acc, 2);
    acc += __shfl_xor(acc, 4); acc += __shfl_xor(acc, 8);
    if (p == 0) gbuf[wd][g] = acc + bih[j] + bhh[j];
    __syncthreads();
    if (t < 4){
        int dd = blockIdx.x*4 + t;
        float iv = gbuf[t][0], fv = gbuf[t][1], gv = gbuf[t][2], ov = gbuf[t][3];
        float cn = sigf(fv)*c[dd] + sigf(iv)*ftanh(gv);
        float hn = sigf(ov)*ftanh(cn);
        c[dd] = cn; hout[dd] = hn;
    }
}

// ---------------------------------------------------------------------------
// ae_loss + sge_enc (singleton softmax == 1)
// ---------------------------------------------------------------------------
__global__ __launch_bounds__(256) void finalize_kernel(
    const float* __restrict__ sg, const float* __restrict__ enc,
    const float* __restrict__ dec, float* __restrict__ sgeenc,
    float* __restrict__ outp)
{
    __shared__ float red[4];
    const int t = threadIdx.x;
    float s = 0.f;
    for (int i = t; i < 1536; i += 256){ float d = sg[i] - dec[i]; s += d*d; }
    s += __shfl_xor(s,1); s += __shfl_xor(s,2); s += __shfl_xor(s,4);
    s += __shfl_xor(s,8); s += __shfl_xor(s,16); s += __shfl_xor(s,32);
    if ((t & 63) == 0) red[t>>6] = s;
    __syncthreads();
    if (t == 0){
        float tot = (red[0]+red[1]+red[2]+red[3]) * (1.f/1536.f);
        outp[2048] = tot;
    }
    for (int d = t; d < 512; d += 256){
        float v = sg[d] + enc[d] + sg[512+d] + enc[512+d] + sg[1024+d] + enc[1024+d];
        sgeenc[d] = v;
        outp[2049 + d] = v;
    }
}

// ---------------------------------------------------------------------------
// wvec[n'] = sum_j sge[j] * qWhh[(n'&3)*1024 + (n'>>2), 512+j]
// ---------------------------------------------------------------------------
__global__ __launch_bounds__(256) void wvec_kernel(
    const float* __restrict__ qWhh, const float* __restrict__ sge,
    float* __restrict__ wvec)
{
    __shared__ float ss[512];
    const int t = threadIdx.x;
    for (int i = t; i < 512; i += 256) ss[i] = sge[i];
    __syncthreads();
    const int n = blockIdx.x * 256 + t;
    const int row = (n & 3) * 1024 + (n >> 2);
    const float4* w = reinterpret_cast<const float4*>(qWhh + (size_t)row*1024 + 512);
    float acc = 0.f;
    for (int kc = 0; kc < 128; kc++){
        float4 wv = w[kc];
        const int kb = kc*4;
        acc += ss[kb]*wv.x + ss[kb+1]*wv.y + ss[kb+2]*wv.z + ss[kb+3]*wv.w;
    }
    wvec[n] = acc;
}

// ---------------------------------------------------------------------------
// Gate math on packed G: g4 = (i,f,g,o) at G[b*2048 + 4d]
// first!=0: treat c as 0 (base step) — removes the cb memset + zero-read.
// ---------------------------------------------------------------------------
__global__ __launch_bounds__(256) void gate_kernel(
    const float* __restrict__ G, const float* __restrict__ qg,
    float* __restrict__ c, u16* __restrict__ h_bf, int first)
{
    const int idx = blockIdx.x * 256 + threadIdx.x;
    const int b = idx >> 9, d = idx & 511;
    float4 g4 = *reinterpret_cast<const float4*>(G + (size_t)b*2048 + d*4);
    float c0 = first ? 0.f : c[idx];
    float cn = sigf(g4.y)*c0 + sigf(g4.x)*ftanh(g4.z);
    float hn = qg[idx] + sigf(g4.w)*ftanh(cn);
    c[idx] = cn; h_bf[idx] = f2b(hn);
}

// ---------------------------------------------------------------------------
// matching_scores[b] = dot(h[b], sge_enc)
// ---------------------------------------------------------------------------
__global__ __launch_bounds__(256) void scores_kernel(
    const u16* __restrict__ h, const float* __restrict__ sge,
    float* __restrict__ out)
{
    const int wave = threadIdx.x >> 6, lane = threadIdx.x & 63;
    const int row = blockIdx.x * 4 + wave;
    const u16* hr = h + (size_t)row * 512;
    float s = 0.f;
    for (int i = lane; i < 512; i += 64) s += b2f(hr[i]) * sge[i];
    s += __shfl_xor(s,1); s += __shfl_xor(s,2); s += __shfl_xor(s,4);
    s += __shfl_xor(s,8); s += __shfl_xor(s,16); s += __shfl_xor(s,32);
    if (lane == 0) out[row] = s;
}

// ---------------------------------------------------------------------------
extern "C" void kernel_launch(void* const* d_in, const int* in_sizes, int n_in,
                              void* d_out, int out_size, void* d_ws, size_t ws_size,
                              hipStream_t stream)
{
    (void)in_sizes; (void)n_in; (void)out_size; (void)ws_size;

    const int* qlc = (const int*)d_in[2];
    const int* qrc = (const int*)d_in[4];
    const int* slc = (const int*)d_in[6];
    const int* src = (const int*)d_in[8];
    const float* emb = (const float*)d_in[10];
    const float* naW = (const float*)d_in[11];
    const float* naB = (const float*)d_in[12];
    const float* nuW = (const float*)d_in[13];
    const float* nuB = (const float*)d_in[14];
    const float* p1W = (const float*)d_in[15], *p1b = (const float*)d_in[16];
    const float* p2W = (const float*)d_in[17], *p2b = (const float*)d_in[18];
    const float* lnA = (const float*)d_in[19], *lnB = (const float*)d_in[20];
    const float* eWih = (const float*)d_in[21], *eWhh = (const float*)d_in[22];
    const float* eBih = (const float*)d_in[23], *eBhh = (const float*)d_in[24];
    const float* dWih = (const float*)d_in[25], *dWhh = (const float*)d_in[26];
    const float* dBih = (const float*)d_in[27], *dBhh = (const float*)d_in[28];
    const float* qWih = (const float*)d_in[33], *qWhh = (const float*)d_in[34];
    const float* qBih = (const float*)d_in[35], *qBhh = (const float*)d_in[36];
    float* out = (float*)d_out;

    float* w = (float*)d_ws;
    size_t off = 0;
    auto alloc = [&](size_t nelem){ float* p = w + off; off += nelem; return p; };
    float* qn    = alloc(2176ull*512);   // neighbor f32 (2051 rows used)
    float* qg    = alloc(2176ull*512);   // query_g f32 (+ sg rows 2048..2050)
    float* enc   = alloc(1536);
    float* dec   = alloc(1536);
    float* zc    = alloc(1024);
    float* sgee  = alloc(512);
    float* wv    = alloc(2048);
    float* bc    = alloc(2048);
    float* nawfF = alloc(65536);         // 131072 u16 frag-packed naW
    float* base  = alloc(2048ull*2048);  // + Zq, qn_bf aliases
    float* G     = alloc(2048ull*2048);  // + Hq_bf, qg_bf aliases
    float* cb    = alloc(2048ull*512);
    float* hbfF  = alloc(524288);        // h bf16
    float* p1WbF = alloc(262144);
    float* p2WbF = alloc(262144);
    float* WihSF = alloc(524288);
    float* WhhSF = alloc(524288);

    u16* nawf   = (u16*)nawfF;
    u16* p1Wb   = (u16*)p1WbF;
    u16* p2Wb   = (u16*)p2WbF;
    u16* WihSel = (u16*)WihSF;
    u16* WhhSel = (u16*)WhhSF;
    u16* h_bf   = (u16*)hbfF;
    float* Zq   = base;                       // 2176x512 f32
    u16* qn_bf  = (u16*)(base + 2097152);     // 2176x512 u16
    u16* Hq_bf  = (u16*)G;                    // 2176x1024 u16
    u16* qg_bf  = (u16*)(G + 2097152);        // 2176x512 u16 (2048 used)
    float* sg   = qg + 2048ull*512;
    float* zbuf = zc;
    float* cst  = zc + 512;

    hipMemsetAsync(zc, 0, 1024*sizeof(float), stream);

    // weight preprocessing (no emb conversion)
    prep_kernel<<<2120, 256, 0, stream>>>(p1W, p2W, naW, qWih, qWhh, qBih, qBhh,
                                          p1Wb, p2Wb, nawf, WihSel, WhhSel, bc);

    // neighbor encoder: 2051 rows (2048 query + 3 support), both sides
    neighbor_v4<<<2051, 256, 0, stream>>>(qlc, qrc, slc, src, emb,
                                          nawf, naB, nuW, nuB, qn, qn_bf);

    // support encoder fused over 2051 rows: H=relu(X@p1W^T+b); Z=H@p2W^T+b; LN
    gemm_tn<<<dim3(16,17), 256, 0, stream>>>(qn_bf, 512, p1Wb, 512, p1b, nullptr, 0,
                                             nullptr, Hq_bf, 1024, 512, 1);
    gemm_tn<<<dim3(8,17), 256, 0, stream>>>(Hq_bf, 1024, p2Wb, 1024, p2b, nullptr, 0,
                                            Zq, nullptr, 512, 1024, 0);
    ln_kernel<<<513, 256, 0, stream>>>(Zq, qn, 2051, 2048, lnA, lnB, qg, qg_bf, out + 2561);

    // set autoencoder
    lstm_small<<<128, 256, 0, stream>>>(sg,        zbuf,      cst, eWih, eWhh, eBih, eBhh, enc);
    lstm_small<<<128, 256, 0, stream>>>(sg + 512,  enc,       cst, eWih, eWhh, eBih, eBhh, enc + 512);
    lstm_small<<<128, 256, 0, stream>>>(sg + 1024, enc + 512, cst, eWih, eWhh, eBih, eBhh, enc + 1024);
    lstm_small<<<128, 256, 0, stream>>>(enc + 1024, enc + 1024, cst, dWih, dWhh, dBih, dBhh, dec);
    lstm_small<<<128, 256, 0, stream>>>(dec,        dec,        cst, dWih, dWhh, dBih, dBhh, dec + 512);
    lstm_small<<<128, 256, 0, stream>>>(dec + 512,  dec + 512,  cst, dWih, dWhh, dBih, dBhh, dec + 1024);

    finalize_kernel<<<1, 256, 0, stream>>>(sg, enc, dec, sgee, out);
    wvec_kernel<<<8, 256, 0, stream>>>(qWhh, sgee, wv);

    // query encoder: base = qg@WihSel^T + bc; 4 steps (live half only)
    gemm_tn<<<dim3(32,16), 256, 0, stream>>>(qg_bf, 512, WihSel, 512, bc, nullptr, 0,
                                             base, nullptr, 2048, 512, 0);
    gate_kernel<<<4096, 256, 0, stream>>>(base, qg, cb, h_bf, 1);
    for (int s = 0; s < 3; s++){
        gemm_tn<<<dim3(32,16), 256, 0, stream>>>(h_bf, 512, WhhSel, 512, wv, base, 2048,
                                                 G, nullptr, 2048, 512, 0);
        gate_kernel<<<4096, 256, 0, stream>>>(G, qg, cb, h_bf, 0);
    }

    scores_kernel<<<512, 256, 0, stream>>>(h_bf, sgee, out);
}